// Round 10
// baseline (122.847 us; speedup 1.0000x reference)
//
#include <hip/hip_runtime.h>

#define N_NODES 8192
#define D_IN 512
#define D_OUT 64
#define LRELU_ALPHA 0.2f
#define KSPLIT 8
#define KSLICE (N_NODES / KSPLIT)   // 1024 cols per block
#define NCHUNK (KSLICE / 256)       // 4 chunks of 256 cols

typedef __attribute__((ext_vector_type(8))) short bf16x8;
typedef __attribute__((ext_vector_type(4))) float f32x4;

__device__ __forceinline__ unsigned short f2bf(float x) {
    unsigned u = __float_as_uint(x);
    u += 0x7fffu + ((u >> 16) & 1u);   // round-to-nearest-even
    return (unsigned short)(u >> 16);
}

__device__ __forceinline__ float pgate(float mk, float w2v, float wh1v, float& lsum) {
    float e = wh1v + w2v;
    e = fmaxf(e, LRELU_ALPHA * e);   // LeakyReLU (monotone)
    float p = mk * __expf(e);        // mask is exactly 0.0/1.0; |e|<=~24 f32-safe
    lsum += p;
    return p;
}

// ---------------- Kernel 1: Wh = h @ W; epilogue writes WhTp(bf16, frag-order), Wh1, Wh2 ----------------
// WhTp layout: per feature n, per 64-col block: shorts [(m>>1)*32 + g*8 + (m&1)*4 + d]
// where col_in_block = g*4 + 16m + d  ->  each MFMA B fragment is one contiguous 16B.
__global__ __launch_bounds__(256) void k_gemm_wh(const float* __restrict__ h,
                                                 const float* __restrict__ W,
                                                 const float* __restrict__ a,
                                                 unsigned short* __restrict__ WhTp,
                                                 float* __restrict__ Wh1,
                                                 float* __restrict__ Wh2) {
    __shared__ float hs[32][68];
    __shared__ float Ws[64][64];
    const int tid = threadIdx.x;
    const int r0 = blockIdx.x * 32;
    const int tf = tid & 15;
    const int tr = tid >> 4;
    float acc[2][4] = {{0.f,0.f,0.f,0.f},{0.f,0.f,0.f,0.f}};

    for (int kc = 0; kc < D_IN; kc += 64) {
        {
            int rr = tid >> 4;
            int cc = (tid & 15) * 4;
            float4 v0 = *(const float4*)&h[(size_t)(r0 + rr) * D_IN + kc + cc];
            float4 v1 = *(const float4*)&h[(size_t)(r0 + rr + 16) * D_IN + kc + cc];
            *(float4*)&hs[rr][cc] = v0;
            *(float4*)&hs[rr + 16][cc] = v1;
        }
        #pragma unroll
        for (int p = 0; p < 4; ++p) {
            int kk = (tid >> 4) + p * 16;
            int cc = (tid & 15) * 4;
            *(float4*)&Ws[kk][cc] = *(const float4*)&W[(size_t)(kc + kk) * D_OUT + cc];
        }
        __syncthreads();
        #pragma unroll
        for (int k = 0; k < 64; k += 4) {
            float4 a0 = *(const float4*)&hs[tr*2][k];
            float4 a1 = *(const float4*)&hs[tr*2+1][k];
            float av0[4] = {a0.x, a0.y, a0.z, a0.w};
            float av1[4] = {a1.x, a1.y, a1.z, a1.w};
            #pragma unroll
            for (int kk = 0; kk < 4; ++kk) {
                float4 b = *(const float4*)&Ws[k+kk][tf*4];
                acc[0][0] += av0[kk]*b.x; acc[0][1] += av0[kk]*b.y;
                acc[0][2] += av0[kk]*b.z; acc[0][3] += av0[kk]*b.w;
                acc[1][0] += av1[kk]*b.x; acc[1][1] += av1[kk]*b.y;
                acc[1][2] += av1[kk]*b.z; acc[1][3] += av1[kk]*b.w;
            }
        }
        __syncthreads();
    }
    const int orow = r0 + tr*2;   // even

    // permuted WhTp write: cols (orow, orow+1) share (g,m), d even -> one 4B store
    {
        const int blk = orow >> 6;
        const int cw  = orow & 63;
        const int d   = cw & 3;
        const int gg  = (cw >> 2) & 3;
        const int m   = cw >> 4;
        const int soff = blk * 64 + (m >> 1) * 32 + gg * 8 + (m & 1) * 4 + d;
        #pragma unroll
        for (int k = 0; k < 4; ++k) {
            unsigned v = (unsigned)f2bf(acc[0][k]) | ((unsigned)f2bf(acc[1][k]) << 16);
            *(unsigned*)&WhTp[(size_t)(tf*4 + k) * N_NODES + soff] = v;
        }
    }

    float a1v[4], a2v[4];
    #pragma unroll
    for (int k = 0; k < 4; ++k) { a1v[k] = a[tf*4 + k]; a2v[k] = a[64 + tf*4 + k]; }
    float s1 = 0.f, t1 = 0.f, s2 = 0.f, t2 = 0.f;
    #pragma unroll
    for (int k = 0; k < 4; ++k) {
        s1 += acc[0][k] * a1v[k];
        t1 += acc[1][k] * a1v[k];
        s2 += acc[0][k] * a2v[k];
        t2 += acc[1][k] * a2v[k];
    }
    #pragma unroll
    for (int d = 1; d < 16; d <<= 1) {
        s1 += __shfl_xor(s1, d);
        t1 += __shfl_xor(t1, d);
        s2 += __shfl_xor(s2, d);
        t2 += __shfl_xor(t2, d);
    }
    if (tf == 0) {
        Wh1[orow] = s1; Wh1[orow + 1] = t1;
        Wh2[orow] = s2; Wh2[orow + 1] = t2;
    }
}

// ---------------- Kernel 2: DMA-pipelined fused mask-stream + MFMA softmax/PV ----------------
// R9 bug: per-iter B-fragment vmem loads were YOUNGER than the prefetch DMAs, so every
// compiler-inserted B-use wait drained the whole DMA queue (depth ~1). Fix: hoist ALL
// 32 B fragments (128 VGPR) into registers BEFORE any DMA issue -- the loop's only vmem
// ops are the 16 DMAs, so hard-coded counted vmcnt waits are exact (and safe under any
// reordering: moved B loads only increase the younger-op count). Depth-3 LDS buffers,
// 2 chunks always in flight (64 KB/CU >> 9 KB needed for per-CU BW saturation).
__global__ __launch_bounds__(256, 2) void k_fused(const float* __restrict__ mask,
                                                  const unsigned short* __restrict__ WhTp,
                                                  const float* __restrict__ Wh1,
                                                  const float* __restrict__ Wh2,
                                                  float* __restrict__ pacc,
                                                  float* __restrict__ plsum) {
    __shared__ float wh2lds[KSLICE];          // 4 KB
    __shared__ float mbuf[3][4][4][256];      // 3 x 16 KB mask chunk buffers [buf][m][wave][lane*4]
    __shared__ float accbuf[4][16][68];       // 17.4 KB
    __shared__ float lsumbuf[4][16];

    const int tid  = threadIdx.x;
    const int wave = tid >> 6;
    const int lane = tid & 63;
    const int i16 = lane & 15;
    const int g   = lane >> 4;
    const int rowblk = blockIdx.x >> 3;
    const int kslice = blockIdx.x & 7;
    const int R   = rowblk * 16;
    const int kbase = kslice * KSLICE;

    // stage Wh2 k-slice (4 KB) once
    *(float4*)&wh2lds[tid * 4] = *(const float4*)&Wh2[kbase + tid * 4];
    const float wh1v = Wh1[R + i16];
    asm volatile("" :: "v"(wh1v));   // materialize before the counted-vmcnt loop
    __syncthreads();

    const unsigned short* bbase = WhTp + (size_t)i16 * N_NODES
                                + (size_t)(kslice * (KSLICE / 64) + wave) * 64 + g * 8;

    f32x4 acc0 = {0.f,0.f,0.f,0.f}, acc1 = {0.f,0.f,0.f,0.f};
    f32x4 acc2 = {0.f,0.f,0.f,0.f}, acc3 = {0.f,0.f,0.f,0.f};
    float lsum = 0.f;

    // ---- prologue A: ALL B fragments -> registers (oldest vmem ops; L2-hot, 1MB) ----
    bf16x8 B0_0,B0_1,B0_2,B0_3,B0_4,B0_5,B0_6,B0_7;
    bf16x8 B1_0,B1_1,B1_2,B1_3,B1_4,B1_5,B1_6,B1_7;
    bf16x8 B2_0,B2_1,B2_2,B2_3,B2_4,B2_5,B2_6,B2_7;
    bf16x8 B3_0,B3_1,B3_2,B3_3,B3_4,B3_5,B3_6,B3_7;
#define BLOAD(cc, V0,V1,V2,V3,V4,V5,V6,V7)                           \
    {                                                                \
        const unsigned short* bb_ = bbase + (cc) * 256;              \
        V0 = *(const bf16x8*)(bb_);                                  \
        V1 = *(const bf16x8*)(bb_ + 32);                             \
        V2 = *(const bf16x8*)(bb_ + 16 * N_NODES);                   \
        V3 = *(const bf16x8*)(bb_ + 16 * N_NODES + 32);              \
        V4 = *(const bf16x8*)(bb_ + 32 * N_NODES);                   \
        V5 = *(const bf16x8*)(bb_ + 32 * N_NODES + 32);              \
        V6 = *(const bf16x8*)(bb_ + 48 * N_NODES);                   \
        V7 = *(const bf16x8*)(bb_ + 48 * N_NODES + 32);              \
    }
    BLOAD(0, B0_0,B0_1,B0_2,B0_3,B0_4,B0_5,B0_6,B0_7);
    BLOAD(1, B1_0,B1_1,B1_2,B1_3,B1_4,B1_5,B1_6,B1_7);
    BLOAD(2, B2_0,B2_1,B2_2,B2_3,B2_4,B2_5,B2_6,B2_7);
    BLOAD(3, B3_0,B3_1,B3_2,B3_3,B3_4,B3_5,B3_6,B3_7);
#undef BLOAD
    __builtin_amdgcn_sched_barrier(0);

    // wave-local DMA: wave stages the granules it will itself read.
    // lane L: 16B from mask[R+(L&15)][kbase + cc*256 + wave*64 + m*16 + (L>>4)*4 ...]
#define DMAISSUE(cc, bi)                                                          \
    {                                                                             \
        const float* gsrc_ = mask + (size_t)(R + i16) * N_NODES                   \
                           + kbase + (cc) * 256 + wave * 64 + g * 4;              \
        __builtin_amdgcn_global_load_lds(gsrc_,      &mbuf[bi][0][wave][0], 16, 0, 0); \
        __builtin_amdgcn_global_load_lds(gsrc_ + 16, &mbuf[bi][1][wave][0], 16, 0, 0); \
        __builtin_amdgcn_global_load_lds(gsrc_ + 32, &mbuf[bi][2][wave][0], 16, 0, 0); \
        __builtin_amdgcn_global_load_lds(gsrc_ + 48, &mbuf[bi][3][wave][0], 16, 0, 0); \
    }

#define PCMF(cc, bi, Q0,Q1,Q2,Q3,Q4,Q5,Q6,Q7)                                     \
    {                                                                             \
        const float4 M0 = *(const float4*)&mbuf[bi][0][wave][lane * 4];           \
        const float4 M1 = *(const float4*)&mbuf[bi][1][wave][lane * 4];           \
        const float4 M2 = *(const float4*)&mbuf[bi][2][wave][lane * 4];           \
        const float4 M3 = *(const float4*)&mbuf[bi][3][wave][lane * 4];           \
        const float4 W0 = *(const float4*)&wh2lds[(cc) * 256 + wave * 64 + g * 4];       \
        const float4 W1 = *(const float4*)&wh2lds[(cc) * 256 + wave * 64 + 16 + g * 4];  \
        const float4 W2 = *(const float4*)&wh2lds[(cc) * 256 + wave * 64 + 32 + g * 4];  \
        const float4 W3 = *(const float4*)&wh2lds[(cc) * 256 + wave * 64 + 48 + g * 4];  \
        bf16x8 af0, af1;                                                          \
        af0[0]=(short)f2bf(pgate(M0.x,W0.x,wh1v,lsum));                           \
        af0[1]=(short)f2bf(pgate(M0.y,W0.y,wh1v,lsum));                           \
        af0[2]=(short)f2bf(pgate(M0.z,W0.z,wh1v,lsum));                           \
        af0[3]=(short)f2bf(pgate(M0.w,W0.w,wh1v,lsum));                           \
        af0[4]=(short)f2bf(pgate(M1.x,W1.x,wh1v,lsum));                           \
        af0[5]=(short)f2bf(pgate(M1.y,W1.y,wh1v,lsum));                           \
        af0[6]=(short)f2bf(pgate(M1.z,W1.z,wh1v,lsum));                           \
        af0[7]=(short)f2bf(pgate(M1.w,W1.w,wh1v,lsum));                           \
        af1[0]=(short)f2bf(pgate(M2.x,W2.x,wh1v,lsum));                           \
        af1[1]=(short)f2bf(pgate(M2.y,W2.y,wh1v,lsum));                           \
        af1[2]=(short)f2bf(pgate(M2.z,W2.z,wh1v,lsum));                           \
        af1[3]=(short)f2bf(pgate(M2.w,W2.w,wh1v,lsum));                           \
        af1[4]=(short)f2bf(pgate(M3.x,W3.x,wh1v,lsum));                           \
        af1[5]=(short)f2bf(pgate(M3.y,W3.y,wh1v,lsum));                           \
        af1[6]=(short)f2bf(pgate(M3.z,W3.z,wh1v,lsum));                           \
        af1[7]=(short)f2bf(pgate(M3.w,W3.w,wh1v,lsum));                           \
        acc0 = __builtin_amdgcn_mfma_f32_16x16x32_bf16(af0, Q0, acc0, 0, 0, 0);   \
        acc1 = __builtin_amdgcn_mfma_f32_16x16x32_bf16(af0, Q2, acc1, 0, 0, 0);   \
        acc2 = __builtin_amdgcn_mfma_f32_16x16x32_bf16(af0, Q4, acc2, 0, 0, 0);   \
        acc3 = __builtin_amdgcn_mfma_f32_16x16x32_bf16(af0, Q6, acc3, 0, 0, 0);   \
        acc0 = __builtin_amdgcn_mfma_f32_16x16x32_bf16(af1, Q1, acc0, 0, 0, 0);   \
        acc1 = __builtin_amdgcn_mfma_f32_16x16x32_bf16(af1, Q3, acc1, 0, 0, 0);   \
        acc2 = __builtin_amdgcn_mfma_f32_16x16x32_bf16(af1, Q5, acc2, 0, 0, 0);   \
        acc3 = __builtin_amdgcn_mfma_f32_16x16x32_bf16(af1, Q7, acc3, 0, 0, 0);   \
    }

#define WAIT(VN) asm volatile("s_waitcnt vmcnt(" VN ")" ::: "memory"); \
                 __builtin_amdgcn_sched_barrier(0)

    // ---- prologue B: depth-3 DMA ----
    DMAISSUE(0, 0);
    DMAISSUE(1, 1);
    DMAISSUE(2, 2);
    __builtin_amdgcn_sched_barrier(0);

    WAIT("8");   // D0 done (D1,D2 in flight; also drains the old B loads)
    PCMF(0, 0, B0_0,B0_1,B0_2,B0_3,B0_4,B0_5,B0_6,B0_7);
    __builtin_amdgcn_sched_barrier(0);
    DMAISSUE(3, 0);                       // buffer 0 reads already consumed
    __builtin_amdgcn_sched_barrier(0);

    WAIT("8");   // D1 done (D2,D3 in flight)
    PCMF(1, 1, B1_0,B1_1,B1_2,B1_3,B1_4,B1_5,B1_6,B1_7);
    __builtin_amdgcn_sched_barrier(0);

    WAIT("4");   // D2 done (D3 in flight)
    PCMF(2, 2, B2_0,B2_1,B2_2,B2_3,B2_4,B2_5,B2_6,B2_7);
    __builtin_amdgcn_sched_barrier(0);

    WAIT("0");   // D3 done
    PCMF(3, 0, B3_0,B3_1,B3_2,B3_3,B3_4,B3_5,B3_6,B3_7);

#undef DMAISSUE
#undef PCMF
#undef WAIT

    // sum lsum across the 4 g-subgroups holding the same row
    lsum += __shfl_xor(lsum, 16);
    lsum += __shfl_xor(lsum, 32);
    if (lane < 16) lsumbuf[wave][lane] = lsum;

    // D layout (m89): row = g*4 + r, col = i16
    #pragma unroll
    for (int r = 0; r < 4; ++r) {
        accbuf[wave][g*4 + r][ 0 + i16] = acc0[r];
        accbuf[wave][g*4 + r][16 + i16] = acc1[r];
        accbuf[wave][g*4 + r][32 + i16] = acc2[r];
        accbuf[wave][g*4 + r][48 + i16] = acc3[r];
    }
    __syncthreads();

    const int tr  = tid >> 4;
    const int tf4 = (tid & 15) * 4;
    float4 s0 = *(const float4*)&accbuf[0][tr][tf4];
    float4 s1 = *(const float4*)&accbuf[1][tr][tf4];
    float4 s2 = *(const float4*)&accbuf[2][tr][tf4];
    float4 s3 = *(const float4*)&accbuf[3][tr][tf4];
    float4 o;
    o.x = s0.x + s1.x + s2.x + s3.x;
    o.y = s0.y + s1.y + s2.y + s3.y;
    o.z = s0.z + s1.z + s2.z + s3.z;
    o.w = s0.w + s1.w + s2.w + s3.w;
    *(float4*)&pacc[((size_t)kslice * N_NODES + R + tr) * D_OUT + tf4] = o;
    if (tid < 16) {
        plsum[(size_t)kslice * N_NODES + R + tid] =
            lsumbuf[0][tid] + lsumbuf[1][tid] +
            lsumbuf[2][tid] + lsumbuf[3][tid];
    }
}

// ---------------- Kernel 3: sum KSPLIT partials, normalize, ELU ----------------
__global__ __launch_bounds__(256) void k_finish(const float* __restrict__ pacc,
                                                const float* __restrict__ plsum,
                                                float* __restrict__ out) {
    const int idx = blockIdx.x * 256 + threadIdx.x;
    const int row = idx >> 4;
    const int tf4 = (idx & 15) * 4;
    float4 s = {0.f, 0.f, 0.f, 0.f};
    float L = 0.f;
    #pragma unroll
    for (int k = 0; k < KSPLIT; ++k) {
        float4 v = *(const float4*)&pacc[((size_t)k * N_NODES + row) * D_OUT + tf4];
        s.x += v.x; s.y += v.y; s.z += v.z; s.w += v.w;
        L += plsum[(size_t)k * N_NODES + row];
    }
    const float inv = (L > 0.f) ? 1.f / L : 0.f;
    float4 o;
    o.x = s.x * inv; o.y = s.y * inv; o.z = s.z * inv; o.w = s.w * inv;
    o.x = (o.x > 0.f) ? o.x : (__expf(o.x) - 1.f);
    o.y = (o.y > 0.f) ? o.y : (__expf(o.y) - 1.f);
    o.z = (o.z > 0.f) ? o.z : (__expf(o.z) - 1.f);
    o.w = (o.w > 0.f) ? o.w : (__expf(o.w) - 1.f);
    *(float4*)&out[(size_t)row * D_OUT + tf4] = o;
}

extern "C" void kernel_launch(void* const* d_in, const int* in_sizes, int n_in,
                              void* d_out, int out_size, void* d_ws, size_t ws_size,
                              hipStream_t stream) {
    const float* h    = (const float*)d_in[0];
    const float* mask = (const float*)d_in[1];
    // d_in[2] = lamda: unused (dischange==0 makes the mask-update a no-op)
    const float* W    = (const float*)d_in[3];
    const float* a    = (const float*)d_in[4];
    float* out = (float*)d_out;

    // ws: WhTp bf16 [64][8192] (1MB) | Wh1 (32KB) | Wh2 (32KB) | pacc (16MB) | plsum (256KB)
    unsigned short* WhTp = (unsigned short*)d_ws;
    float* Wh1 = (float*)((char*)d_ws + (size_t)D_OUT * N_NODES * sizeof(unsigned short));
    float* Wh2 = Wh1 + N_NODES;
    float* pacc = Wh2 + N_NODES;
    float* plsum = pacc + (size_t)KSPLIT * N_NODES * D_OUT;

    k_gemm_wh<<<N_NODES / 32, 256, 0, stream>>>(h, W, a, WhTp, Wh1, Wh2);
    k_fused<<<(N_NODES / 16) * KSPLIT, 256, 0, stream>>>(mask, WhTp, Wh1, Wh2, pacc, plsum);
    k_finish<<<(N_NODES * D_OUT / 4) / 256, 256, 0, stream>>>(pacc, plsum, out);
}

// Round 11
// 116.541 us; speedup vs baseline: 1.0541x; 1.0541x over previous
//
#include <hip/hip_runtime.h>

#define N_NODES 8192
#define D_IN 512
#define D_OUT 64
#define LRELU_ALPHA 0.2f
#define KSPLIT 8
#define KSLICE (N_NODES / KSPLIT)   // 1024 cols per block; each wave owns 256 contiguous

typedef __attribute__((ext_vector_type(8))) short bf16x8;
typedef __attribute__((ext_vector_type(4))) float f32x4;

__device__ __forceinline__ unsigned short f2bf(float x) {
    unsigned u = __float_as_uint(x);
    u += 0x7fffu + ((u >> 16) & 1u);   // round-to-nearest-even
    return (unsigned short)(u >> 16);
}

__device__ __forceinline__ float pgate(float mk, float w2v, float wh1v, float& lsum) {
    float e = wh1v + w2v;
    e = fmaxf(e, LRELU_ALPHA * e);   // LeakyReLU (monotone)
    float p = mk * __expf(e);        // mask is exactly 0.0/1.0; |e|<=~24 f32-safe
    lsum += p;
    return p;
}

// ---------------- Kernel 1: Wh = h @ W; epilogue writes WhTp(bf16, frag-order), Wh1, Wh2 ----------------
// WhTp layout: per feature n, per 64-col block: shorts [(m>>1)*32 + g*8 + (m&1)*4 + d]
// where col_in_block = g*4 + 16m + d  ->  each MFMA B fragment is one contiguous 16B.
__global__ __launch_bounds__(256) void k_gemm_wh(const float* __restrict__ h,
                                                 const float* __restrict__ W,
                                                 const float* __restrict__ a,
                                                 unsigned short* __restrict__ WhTp,
                                                 float* __restrict__ Wh1,
                                                 float* __restrict__ Wh2) {
    __shared__ float hs[32][68];
    __shared__ float Ws[64][64];
    const int tid = threadIdx.x;
    const int r0 = blockIdx.x * 32;
    const int tf = tid & 15;
    const int tr = tid >> 4;
    float acc[2][4] = {{0.f,0.f,0.f,0.f},{0.f,0.f,0.f,0.f}};

    for (int kc = 0; kc < D_IN; kc += 64) {
        {
            int rr = tid >> 4;
            int cc = (tid & 15) * 4;
            float4 v0 = *(const float4*)&h[(size_t)(r0 + rr) * D_IN + kc + cc];
            float4 v1 = *(const float4*)&h[(size_t)(r0 + rr + 16) * D_IN + kc + cc];
            *(float4*)&hs[rr][cc] = v0;
            *(float4*)&hs[rr + 16][cc] = v1;
        }
        #pragma unroll
        for (int p = 0; p < 4; ++p) {
            int kk = (tid >> 4) + p * 16;
            int cc = (tid & 15) * 4;
            *(float4*)&Ws[kk][cc] = *(const float4*)&W[(size_t)(kc + kk) * D_OUT + cc];
        }
        __syncthreads();
        #pragma unroll
        for (int k = 0; k < 64; k += 4) {
            float4 a0 = *(const float4*)&hs[tr*2][k];
            float4 a1 = *(const float4*)&hs[tr*2+1][k];
            float av0[4] = {a0.x, a0.y, a0.z, a0.w};
            float av1[4] = {a1.x, a1.y, a1.z, a1.w};
            #pragma unroll
            for (int kk = 0; kk < 4; ++kk) {
                float4 b = *(const float4*)&Ws[k+kk][tf*4];
                acc[0][0] += av0[kk]*b.x; acc[0][1] += av0[kk]*b.y;
                acc[0][2] += av0[kk]*b.z; acc[0][3] += av0[kk]*b.w;
                acc[1][0] += av1[kk]*b.x; acc[1][1] += av1[kk]*b.y;
                acc[1][2] += av1[kk]*b.z; acc[1][3] += av1[kk]*b.w;
            }
        }
        __syncthreads();
    }
    const int orow = r0 + tr*2;   // even

    // permuted WhTp write: cols (orow, orow+1) share (g,m), d even -> one 4B store
    {
        const int blk = orow >> 6;
        const int cw  = orow & 63;
        const int d   = cw & 3;
        const int gg  = (cw >> 2) & 3;
        const int m   = cw >> 4;
        const int soff = blk * 64 + (m >> 1) * 32 + gg * 8 + (m & 1) * 4 + d;
        #pragma unroll
        for (int k = 0; k < 4; ++k) {
            unsigned v = (unsigned)f2bf(acc[0][k]) | ((unsigned)f2bf(acc[1][k]) << 16);
            *(unsigned*)&WhTp[(size_t)(tf*4 + k) * N_NODES + soff] = v;
        }
    }

    float a1v[4], a2v[4];
    #pragma unroll
    for (int k = 0; k < 4; ++k) { a1v[k] = a[tf*4 + k]; a2v[k] = a[64 + tf*4 + k]; }
    float s1 = 0.f, t1 = 0.f, s2 = 0.f, t2 = 0.f;
    #pragma unroll
    for (int k = 0; k < 4; ++k) {
        s1 += acc[0][k] * a1v[k];
        t1 += acc[1][k] * a1v[k];
        s2 += acc[0][k] * a2v[k];
        t2 += acc[1][k] * a2v[k];
    }
    #pragma unroll
    for (int d = 1; d < 16; d <<= 1) {
        s1 += __shfl_xor(s1, d);
        t1 += __shfl_xor(t1, d);
        s2 += __shfl_xor(s2, d);
        t2 += __shfl_xor(t2, d);
    }
    if (tf == 0) {
        Wh1[orow] = s1; Wh1[orow + 1] = t1;
        Wh2[orow] = s2; Wh2[orow + 1] = t2;
    }
}

// ---------------- Kernel 2: row-contiguous-DMA fused mask-stream + MFMA softmax/PV ----------------
// Wave w owns the CONTIGUOUS 256-col window [w*256, w*256+256) of the block's kslice:
//  - 16 DMA instructions/wave, each = one row's 1KB (64 lanes x 16B contiguous) -> perfect
//    line-granular coalescing (R10's 16x64B scatter per instr is the diagnosed BW cap).
//  - XOR swizzle (phys = logical ^ ((row&7)<<4)) applied on the per-lane GLOBAL source
//    (lane ^ (r&7); LDS dest stays linear per m104) and on the ds_read address -> 2-way
//    bank aliasing only (free, m136).
//  - one wait: vmcnt(0) after issuing all 16 DMAs; no barriers in flight; latency hidden
//    by 8 independent waves/CU with 16KB each outstanding (128KB/CU >> 9KB BW-latency product).
//  - all 32 B fragments (128 VGPR) hoisted before the DMAs (vmcnt(0) drains them too).
//  - accbuf/lsumbuf aliased onto dead mbuf space after compute (LDS 68.25KB -> 2 blocks/CU).
__global__ __launch_bounds__(256, 2) void k_fused(const float* __restrict__ mask,
                                                  const unsigned short* __restrict__ WhTp,
                                                  const float* __restrict__ Wh1,
                                                  const float* __restrict__ Wh2,
                                                  float* __restrict__ pacc,
                                                  float* __restrict__ plsum) {
    __shared__ float wh2lds[KSLICE];          // 4 KB
    __shared__ float mbuf[4][16][256];        // 64 KB: [wave][row][swizzled col]
    float (*accbuf)[16][68] = reinterpret_cast<float (*)[16][68]>(&mbuf[0][0][0]);
    float (*lsumbuf)[16]    = reinterpret_cast<float (*)[16]>(&mbuf[0][0][0] + 4*16*68);

    const int tid  = threadIdx.x;
    const int wave = tid >> 6;
    const int lane = tid & 63;
    const int i16 = lane & 15;
    const int g   = lane >> 4;
    const int rowblk = blockIdx.x >> 3;
    const int kslice = blockIdx.x & 7;
    const int R   = rowblk * 16;
    const int kbase = kslice * KSLICE;

    // stage Wh2 k-slice (4 KB) once
    *(float4*)&wh2lds[tid * 4] = *(const float4*)&Wh2[kbase + tid * 4];
    const float wh1v = Wh1[R + i16];
    __syncthreads();

    f32x4 acc0 = {0.f,0.f,0.f,0.f}, acc1 = {0.f,0.f,0.f,0.f};
    f32x4 acc2 = {0.f,0.f,0.f,0.f}, acc3 = {0.f,0.f,0.f,0.f};
    float lsum = 0.f;

    // ---- prologue A: this wave's 32 B fragments -> registers (L2-hot, 1MB total) ----
    // col-block index for (wave, g64) = kslice*16 + wave*4 + g64
    const unsigned short* bbase = WhTp + (size_t)i16 * N_NODES
                                + (size_t)(kslice * 16 + wave * 4) * 64 + g * 8;
    bf16x8 B0_0,B0_1,B0_2,B0_3,B0_4,B0_5,B0_6,B0_7;
    bf16x8 B1_0,B1_1,B1_2,B1_3,B1_4,B1_5,B1_6,B1_7;
    bf16x8 B2_0,B2_1,B2_2,B2_3,B2_4,B2_5,B2_6,B2_7;
    bf16x8 B3_0,B3_1,B3_2,B3_3,B3_4,B3_5,B3_6,B3_7;
#define BLOAD(g64, V0,V1,V2,V3,V4,V5,V6,V7)                          \
    {                                                                \
        const unsigned short* bb_ = bbase + (g64) * 64;              \
        V0 = *(const bf16x8*)(bb_);                                  \
        V1 = *(const bf16x8*)(bb_ + 32);                             \
        V2 = *(const bf16x8*)(bb_ + 16 * N_NODES);                   \
        V3 = *(const bf16x8*)(bb_ + 16 * N_NODES + 32);              \
        V4 = *(const bf16x8*)(bb_ + 32 * N_NODES);                   \
        V5 = *(const bf16x8*)(bb_ + 32 * N_NODES + 32);              \
        V6 = *(const bf16x8*)(bb_ + 48 * N_NODES);                   \
        V7 = *(const bf16x8*)(bb_ + 48 * N_NODES + 32);              \
    }
    BLOAD(0, B0_0,B0_1,B0_2,B0_3,B0_4,B0_5,B0_6,B0_7);
    BLOAD(1, B1_0,B1_1,B1_2,B1_3,B1_4,B1_5,B1_6,B1_7);
    BLOAD(2, B2_0,B2_1,B2_2,B2_3,B2_4,B2_5,B2_6,B2_7);
    BLOAD(3, B3_0,B3_1,B3_2,B3_3,B3_4,B3_5,B3_6,B3_7);
#undef BLOAD
    __builtin_amdgcn_sched_barrier(0);

    // ---- prologue B: 16 row-contiguous DMAs (1KB each), source pre-swizzled ----
    {
        const float* mrow = mask + (size_t)R * N_NODES + kbase + wave * 256;
        #pragma unroll
        for (int r = 0; r < 16; ++r) {
            const float* src = mrow + (size_t)r * N_NODES + ((lane ^ (r & 7)) << 2);
            __builtin_amdgcn_global_load_lds(src, &mbuf[wave][r][0], 16, 0, 0);
        }
    }
    __builtin_amdgcn_sched_barrier(0);
    asm volatile("s_waitcnt vmcnt(0)" ::: "memory");   // drains DMAs (and the older B loads)
    __builtin_amdgcn_sched_barrier(0);

    // ---- compute: 4 x 64-col groups; M from swizzled LDS, W broadcast, MFMA ----
    // granule m read: phys float = (g64*64 + m*16 + g*4) ^ ((i16&7)<<2), row i16
#define PCMF(g64, Q0,Q1,Q2,Q3,Q4,Q5,Q6,Q7)                                        \
    {                                                                             \
        const int sw_ = (i16 & 7) << 2;                                           \
        const float4 M0 = *(const float4*)&mbuf[wave][i16][((g64)*64 +  0 + g*4) ^ sw_]; \
        const float4 M1 = *(const float4*)&mbuf[wave][i16][((g64)*64 + 16 + g*4) ^ sw_]; \
        const float4 M2 = *(const float4*)&mbuf[wave][i16][((g64)*64 + 32 + g*4) ^ sw_]; \
        const float4 M3 = *(const float4*)&mbuf[wave][i16][((g64)*64 + 48 + g*4) ^ sw_]; \
        const float4 W0 = *(const float4*)&wh2lds[wave*256 + (g64)*64 +  0 + g*4];       \
        const float4 W1 = *(const float4*)&wh2lds[wave*256 + (g64)*64 + 16 + g*4];       \
        const float4 W2 = *(const float4*)&wh2lds[wave*256 + (g64)*64 + 32 + g*4];       \
        const float4 W3 = *(const float4*)&wh2lds[wave*256 + (g64)*64 + 48 + g*4];       \
        bf16x8 af0, af1;                                                          \
        af0[0]=(short)f2bf(pgate(M0.x,W0.x,wh1v,lsum));                           \
        af0[1]=(short)f2bf(pgate(M0.y,W0.y,wh1v,lsum));                           \
        af0[2]=(short)f2bf(pgate(M0.z,W0.z,wh1v,lsum));                           \
        af0[3]=(short)f2bf(pgate(M0.w,W0.w,wh1v,lsum));                           \
        af0[4]=(short)f2bf(pgate(M1.x,W1.x,wh1v,lsum));                           \
        af0[5]=(short)f2bf(pgate(M1.y,W1.y,wh1v,lsum));                           \
        af0[6]=(short)f2bf(pgate(M1.z,W1.z,wh1v,lsum));                           \
        af0[7]=(short)f2bf(pgate(M1.w,W1.w,wh1v,lsum));                           \
        af1[0]=(short)f2bf(pgate(M2.x,W2.x,wh1v,lsum));                           \
        af1[1]=(short)f2bf(pgate(M2.y,W2.y,wh1v,lsum));                           \
        af1[2]=(short)f2bf(pgate(M2.z,W2.z,wh1v,lsum));                           \
        af1[3]=(short)f2bf(pgate(M2.w,W2.w,wh1v,lsum));                           \
        af1[4]=(short)f2bf(pgate(M3.x,W3.x,wh1v,lsum));                           \
        af1[5]=(short)f2bf(pgate(M3.y,W3.y,wh1v,lsum));                           \
        af1[6]=(short)f2bf(pgate(M3.z,W3.z,wh1v,lsum));                           \
        af1[7]=(short)f2bf(pgate(M3.w,W3.w,wh1v,lsum));                           \
        acc0 = __builtin_amdgcn_mfma_f32_16x16x32_bf16(af0, Q0, acc0, 0, 0, 0);   \
        acc1 = __builtin_amdgcn_mfma_f32_16x16x32_bf16(af0, Q2, acc1, 0, 0, 0);   \
        acc2 = __builtin_amdgcn_mfma_f32_16x16x32_bf16(af0, Q4, acc2, 0, 0, 0);   \
        acc3 = __builtin_amdgcn_mfma_f32_16x16x32_bf16(af0, Q6, acc3, 0, 0, 0);   \
        acc0 = __builtin_amdgcn_mfma_f32_16x16x32_bf16(af1, Q1, acc0, 0, 0, 0);   \
        acc1 = __builtin_amdgcn_mfma_f32_16x16x32_bf16(af1, Q3, acc1, 0, 0, 0);   \
        acc2 = __builtin_amdgcn_mfma_f32_16x16x32_bf16(af1, Q5, acc2, 0, 0, 0);   \
        acc3 = __builtin_amdgcn_mfma_f32_16x16x32_bf16(af1, Q7, acc3, 0, 0, 0);   \
    }

    PCMF(0, B0_0,B0_1,B0_2,B0_3,B0_4,B0_5,B0_6,B0_7);
    PCMF(1, B1_0,B1_1,B1_2,B1_3,B1_4,B1_5,B1_6,B1_7);
    PCMF(2, B2_0,B2_1,B2_2,B2_3,B2_4,B2_5,B2_6,B2_7);
    PCMF(3, B3_0,B3_1,B3_2,B3_3,B3_4,B3_5,B3_6,B3_7);
#undef PCMF

    // sum lsum across the 4 g-subgroups holding the same row
    lsum += __shfl_xor(lsum, 16);
    lsum += __shfl_xor(lsum, 32);

    __syncthreads();   // all waves done reading mbuf before aliasing it as accbuf

    // D layout (m89): row = g*4 + r, col = i16
    #pragma unroll
    for (int r = 0; r < 4; ++r) {
        accbuf[wave][g*4 + r][ 0 + i16] = acc0[r];
        accbuf[wave][g*4 + r][16 + i16] = acc1[r];
        accbuf[wave][g*4 + r][32 + i16] = acc2[r];
        accbuf[wave][g*4 + r][48 + i16] = acc3[r];
    }
    if (lane < 16) lsumbuf[wave][lane] = lsum;
    __syncthreads();

    const int tr  = tid >> 4;
    const int tf4 = (tid & 15) * 4;
    float4 s0 = *(const float4*)&accbuf[0][tr][tf4];
    float4 s1 = *(const float4*)&accbuf[1][tr][tf4];
    float4 s2 = *(const float4*)&accbuf[2][tr][tf4];
    float4 s3 = *(const float4*)&accbuf[3][tr][tf4];
    float4 o;
    o.x = s0.x + s1.x + s2.x + s3.x;
    o.y = s0.y + s1.y + s2.y + s3.y;
    o.z = s0.z + s1.z + s2.z + s3.z;
    o.w = s0.w + s1.w + s2.w + s3.w;
    *(float4*)&pacc[((size_t)kslice * N_NODES + R + tr) * D_OUT + tf4] = o;
    if (tid < 16) {
        plsum[(size_t)kslice * N_NODES + R + tid] =
            lsumbuf[0][tid] + lsumbuf[1][tid] +
            lsumbuf[2][tid] + lsumbuf[3][tid];
    }
}

// ---------------- Kernel 3: sum KSPLIT partials, normalize, ELU ----------------
__global__ __launch_bounds__(256) void k_finish(const float* __restrict__ pacc,
                                                const float* __restrict__ plsum,
                                                float* __restrict__ out) {
    const int idx = blockIdx.x * 256 + threadIdx.x;
    const int row = idx >> 4;
    const int tf4 = (idx & 15) * 4;
    float4 s = {0.f, 0.f, 0.f, 0.f};
    float L = 0.f;
    #pragma unroll
    for (int k = 0; k < KSPLIT; ++k) {
        float4 v = *(const float4*)&pacc[((size_t)k * N_NODES + row) * D_OUT + tf4];
        s.x += v.x; s.y += v.y; s.z += v.z; s.w += v.w;
        L += plsum[(size_t)k * N_NODES + row];
    }
    const float inv = (L > 0.f) ? 1.f / L : 0.f;
    float4 o;
    o.x = s.x * inv; o.y = s.y * inv; o.z = s.z * inv; o.w = s.w * inv;
    o.x = (o.x > 0.f) ? o.x : (__expf(o.x) - 1.f);
    o.y = (o.y > 0.f) ? o.y : (__expf(o.y) - 1.f);
    o.z = (o.z > 0.f) ? o.z : (__expf(o.z) - 1.f);
    o.w = (o.w > 0.f) ? o.w : (__expf(o.w) - 1.f);
    *(float4*)&out[(size_t)row * D_OUT + tf4] = o;
}

extern "C" void kernel_launch(void* const* d_in, const int* in_sizes, int n_in,
                              void* d_out, int out_size, void* d_ws, size_t ws_size,
                              hipStream_t stream) {
    const float* h    = (const float*)d_in[0];
    const float* mask = (const float*)d_in[1];
    // d_in[2] = lamda: unused (dischange==0 makes the mask-update a no-op)
    const float* W    = (const float*)d_in[3];
    const float* a    = (const float*)d_in[4];
    float* out = (float*)d_out;

    // ws: WhTp bf16 [64][8192] (1MB) | Wh1 (32KB) | Wh2 (32KB) | pacc (16MB) | plsum (256KB)
    unsigned short* WhTp = (unsigned short*)d_ws;
    float* Wh1 = (float*)((char*)d_ws + (size_t)D_OUT * N_NODES * sizeof(unsigned short));
    float* Wh2 = Wh1 + N_NODES;
    float* pacc = Wh2 + N_NODES;
    float* plsum = pacc + (size_t)KSPLIT * N_NODES * D_OUT;

    k_gemm_wh<<<N_NODES / 32, 256, 0, stream>>>(h, W, a, WhTp, Wh1, Wh2);
    k_fused<<<(N_NODES / 16) * KSPLIT, 256, 0, stream>>>(mask, WhTp, Wh1, Wh2, pacc, plsum);
    k_finish<<<(N_NODES * D_OUT / 4) / 256, 256, 0, stream>>>(pacc, plsum, out);
}

// Round 12
// 109.996 us; speedup vs baseline: 1.1168x; 1.0595x over previous
//
#include <hip/hip_runtime.h>

#define N_NODES 8192
#define D_IN 512
#define D_OUT 64
#define LRELU_ALPHA 0.2f

typedef __attribute__((ext_vector_type(8))) short bf16x8;
typedef __attribute__((ext_vector_type(4))) float f32x4;

__device__ __forceinline__ unsigned short f2bf(float x) {
    unsigned u = __float_as_uint(x);
    u += 0x7fffu + ((u >> 16) & 1u);   // round-to-nearest-even
    return (unsigned short)(u >> 16);
}

__device__ __forceinline__ float pgate(float mk, float w2v, float wh1v, float& lsum) {
    float e = wh1v + w2v;
    e = fmaxf(e, LRELU_ALPHA * e);   // LeakyReLU (monotone)
    float p = mk * __expf(e);        // mask is exactly 0.0/1.0; |e|<=~24 f32-safe
    lsum += p;
    return p;
}

// ---------------- Kernel 1: Wh = h @ W; epilogue writes WhTp(bf16, frag-order), Wh1, Wh2 ----------------
__global__ __launch_bounds__(256) void k_gemm_wh(const float* __restrict__ h,
                                                 const float* __restrict__ W,
                                                 const float* __restrict__ a,
                                                 unsigned short* __restrict__ WhTp,
                                                 float* __restrict__ Wh1,
                                                 float* __restrict__ Wh2) {
    __shared__ float hs[32][68];
    __shared__ float Ws[64][64];
    const int tid = threadIdx.x;
    const int r0 = blockIdx.x * 32;
    const int tf = tid & 15;
    const int tr = tid >> 4;
    float acc[2][4] = {{0.f,0.f,0.f,0.f},{0.f,0.f,0.f,0.f}};

    for (int kc = 0; kc < D_IN; kc += 64) {
        {
            int rr = tid >> 4;
            int cc = (tid & 15) * 4;
            float4 v0 = *(const float4*)&h[(size_t)(r0 + rr) * D_IN + kc + cc];
            float4 v1 = *(const float4*)&h[(size_t)(r0 + rr + 16) * D_IN + kc + cc];
            *(float4*)&hs[rr][cc] = v0;
            *(float4*)&hs[rr + 16][cc] = v1;
        }
        #pragma unroll
        for (int p = 0; p < 4; ++p) {
            int kk = (tid >> 4) + p * 16;
            int cc = (tid & 15) * 4;
            *(float4*)&Ws[kk][cc] = *(const float4*)&W[(size_t)(kc + kk) * D_OUT + cc];
        }
        __syncthreads();
        #pragma unroll
        for (int k = 0; k < 64; k += 4) {
            float4 a0 = *(const float4*)&hs[tr*2][k];
            float4 a1 = *(const float4*)&hs[tr*2+1][k];
            float av0[4] = {a0.x, a0.y, a0.z, a0.w};
            float av1[4] = {a1.x, a1.y, a1.z, a1.w};
            #pragma unroll
            for (int kk = 0; kk < 4; ++kk) {
                float4 b = *(const float4*)&Ws[k+kk][tf*4];
                acc[0][0] += av0[kk]*b.x; acc[0][1] += av0[kk]*b.y;
                acc[0][2] += av0[kk]*b.z; acc[0][3] += av0[kk]*b.w;
                acc[1][0] += av1[kk]*b.x; acc[1][1] += av1[kk]*b.y;
                acc[1][2] += av1[kk]*b.z; acc[1][3] += av1[kk]*b.w;
            }
        }
        __syncthreads();
    }
    const int orow = r0 + tr*2;   // even

    // permuted WhTp write: each MFMA B fragment is one contiguous 16B
    {
        const int blk = orow >> 6;
        const int cw  = orow & 63;
        const int d   = cw & 3;
        const int gg  = (cw >> 2) & 3;
        const int m   = cw >> 4;
        const int soff = blk * 64 + (m >> 1) * 32 + gg * 8 + (m & 1) * 4 + d;
        #pragma unroll
        for (int k = 0; k < 4; ++k) {
            unsigned v = (unsigned)f2bf(acc[0][k]) | ((unsigned)f2bf(acc[1][k]) << 16);
            *(unsigned*)&WhTp[(size_t)(tf*4 + k) * N_NODES + soff] = v;
        }
    }

    float a1v[4], a2v[4];
    #pragma unroll
    for (int k = 0; k < 4; ++k) { a1v[k] = a[tf*4 + k]; a2v[k] = a[64 + tf*4 + k]; }
    float s1 = 0.f, t1 = 0.f, s2 = 0.f, t2 = 0.f;
    #pragma unroll
    for (int k = 0; k < 4; ++k) {
        s1 += acc[0][k] * a1v[k];
        t1 += acc[1][k] * a1v[k];
        s2 += acc[0][k] * a2v[k];
        t2 += acc[1][k] * a2v[k];
    }
    #pragma unroll
    for (int d = 1; d < 16; d <<= 1) {
        s1 += __shfl_xor(s1, d);
        t1 += __shfl_xor(t1, d);
        s2 += __shfl_xor(s2, d);
        t2 += __shfl_xor(t2, d);
    }
    if (tf == 0) {
        Wh1[orow] = s1; Wh1[orow + 1] = t1;
        Wh2[orow] = s2; Wh2[orow + 1] = t2;
    }
}

// ---------------- Kernel 2: persistent full-row fused mask-stream + MFMA softmax/PV ----------------
// 512 blocks, one per 16-row strip; each streams its FULL 512KB mask strip in 32 chunks
// (64 cols/wave/chunk) with a rolling 3-deep counted-vmcnt pipeline. Per chunk one 16-op
// vmem group {8 B-frag + 4 Wh2 + 4 DMA(1KB row-quad, XOR-pre-swizzled src)} -> group
// counting stays exact (B/W grouped WITH their chunk, R9 lesson). 3 named register sets,
// zero barriers in the loop, prologue/epilogue amortized over 512KB (R11's killer was
// 3-4us overhead per 64KB block). Full row per block => softmax finished in-block,
// k_finish + pacc round-trip deleted.
__global__ __launch_bounds__(256) void k_fused(const float* __restrict__ mask,
                                               const unsigned short* __restrict__ WhTp,
                                               const float* __restrict__ Wh1,
                                               const float* __restrict__ Wh2,
                                               float* __restrict__ out) {
    __shared__ float mbuf[3][4][16][64];   // 48 KB: [set][wave][row][swizzled col]
    float (*accbuf)[16][68] = reinterpret_cast<float (*)[16][68]>(&mbuf[0][0][0][0]);
    float (*lsumbuf)[16]    = reinterpret_cast<float (*)[16]>(&mbuf[0][0][0][0] + 4*16*68);

    const int tid  = threadIdx.x;
    const int wave = tid >> 6;
    const int lane = tid & 63;
    const int i16 = lane & 15;
    const int g   = lane >> 4;
    const int R   = blockIdx.x * 16;

    const float wh1v = Wh1[R + i16];

    f32x4 acc0 = {0.f,0.f,0.f,0.f}, acc1 = {0.f,0.f,0.f,0.f};
    f32x4 acc2 = {0.f,0.f,0.f,0.f}, acc3 = {0.f,0.f,0.f,0.f};
    float lsum = 0.f;

    const float* mstrip = mask + (size_t)R * N_NODES;

    // 3 named register sets (chunk k -> set k%3)
#define DECLSET(S) \
    bf16x8 B##S##_0, B##S##_1, B##S##_2, B##S##_3, B##S##_4, B##S##_5, B##S##_6, B##S##_7; \
    float4 W##S##_0, W##S##_1, W##S##_2, W##S##_3;
    DECLSET(0) DECLSET(1) DECLSET(2)
#undef DECLSET

    // one vmem group per chunk: 8 B-frag loads + 4 Wh2 loads + 4 DMA = 16 ops
    // DMA j covers rows 4j..4j+3 (1KB contiguous dest; src col pre-swizzled by row&7)
#define ISSUE(c, S)                                                                    \
    {                                                                                  \
        __builtin_amdgcn_sched_barrier(0);                                             \
        const int win_ = (c) * 256 + wave * 64;                                        \
        const unsigned short* bb_ = WhTp + (size_t)i16 * N_NODES                       \
                                  + (size_t)((c) * 4 + wave) * 64 + g * 8;             \
        B##S##_0 = *(const bf16x8*)(bb_);                                              \
        B##S##_1 = *(const bf16x8*)(bb_ + 32);                                         \
        B##S##_2 = *(const bf16x8*)(bb_ + 16 * N_NODES);                               \
        B##S##_3 = *(const bf16x8*)(bb_ + 16 * N_NODES + 32);                          \
        B##S##_4 = *(const bf16x8*)(bb_ + 32 * N_NODES);                               \
        B##S##_5 = *(const bf16x8*)(bb_ + 32 * N_NODES + 32);                          \
        B##S##_6 = *(const bf16x8*)(bb_ + 48 * N_NODES);                               \
        B##S##_7 = *(const bf16x8*)(bb_ + 48 * N_NODES + 32);                          \
        const float* wp_ = Wh2 + win_ + g * 4;                                         \
        W##S##_0 = *(const float4*)(wp_);                                              \
        W##S##_1 = *(const float4*)(wp_ + 16);                                         \
        W##S##_2 = *(const float4*)(wp_ + 32);                                         \
        W##S##_3 = *(const float4*)(wp_ + 48);                                         \
        const float* ms_ = mstrip + win_;                                              \
        const float* s0_ = ms_ + (size_t)(0  + g) * N_NODES + ((i16 ^ ((0  + g) & 7)) << 2); \
        const float* s1_ = ms_ + (size_t)(4  + g) * N_NODES + ((i16 ^ ((4  + g) & 7)) << 2); \
        const float* s2_ = ms_ + (size_t)(8  + g) * N_NODES + ((i16 ^ ((8  + g) & 7)) << 2); \
        const float* s3_ = ms_ + (size_t)(12 + g) * N_NODES + ((i16 ^ ((12 + g) & 7)) << 2); \
        __builtin_amdgcn_global_load_lds(s0_, &mbuf[S][wave][ 0][0], 16, 0, 0);        \
        __builtin_amdgcn_global_load_lds(s1_, &mbuf[S][wave][ 4][0], 16, 0, 0);        \
        __builtin_amdgcn_global_load_lds(s2_, &mbuf[S][wave][ 8][0], 16, 0, 0);        \
        __builtin_amdgcn_global_load_lds(s3_, &mbuf[S][wave][12][0], 16, 0, 0);        \
        __builtin_amdgcn_sched_barrier(0);                                             \
    }

    // read this lane's row (i16): phys float4-slot = (m*4+g) ^ (i16&7)
#define COMPUTE(S, VN)                                                                 \
    {                                                                                  \
        asm volatile("s_waitcnt vmcnt(" VN ")" ::: "memory");                          \
        __builtin_amdgcn_sched_barrier(0);                                             \
        const int sw_ = i16 & 7;                                                       \
        const float4 M0 = *(const float4*)&mbuf[S][wave][i16][((0*4+g) ^ sw_) << 2];   \
        const float4 M1 = *(const float4*)&mbuf[S][wave][i16][((1*4+g) ^ sw_) << 2];   \
        const float4 M2 = *(const float4*)&mbuf[S][wave][i16][((2*4+g) ^ sw_) << 2];   \
        const float4 M3 = *(const float4*)&mbuf[S][wave][i16][((3*4+g) ^ sw_) << 2];   \
        bf16x8 af0, af1;                                                               \
        af0[0]=(short)f2bf(pgate(M0.x, W##S##_0.x, wh1v, lsum));                       \
        af0[1]=(short)f2bf(pgate(M0.y, W##S##_0.y, wh1v, lsum));                       \
        af0[2]=(short)f2bf(pgate(M0.z, W##S##_0.z, wh1v, lsum));                       \
        af0[3]=(short)f2bf(pgate(M0.w, W##S##_0.w, wh1v, lsum));                       \
        af0[4]=(short)f2bf(pgate(M1.x, W##S##_1.x, wh1v, lsum));                       \
        af0[5]=(short)f2bf(pgate(M1.y, W##S##_1.y, wh1v, lsum));                       \
        af0[6]=(short)f2bf(pgate(M1.z, W##S##_1.z, wh1v, lsum));                       \
        af0[7]=(short)f2bf(pgate(M1.w, W##S##_1.w, wh1v, lsum));                       \
        af1[0]=(short)f2bf(pgate(M2.x, W##S##_2.x, wh1v, lsum));                       \
        af1[1]=(short)f2bf(pgate(M2.y, W##S##_2.y, wh1v, lsum));                       \
        af1[2]=(short)f2bf(pgate(M2.z, W##S##_2.z, wh1v, lsum));                       \
        af1[3]=(short)f2bf(pgate(M2.w, W##S##_2.w, wh1v, lsum));                       \
        af1[4]=(short)f2bf(pgate(M3.x, W##S##_3.x, wh1v, lsum));                       \
        af1[5]=(short)f2bf(pgate(M3.y, W##S##_3.y, wh1v, lsum));                       \
        af1[6]=(short)f2bf(pgate(M3.z, W##S##_3.z, wh1v, lsum));                       \
        af1[7]=(short)f2bf(pgate(M3.w, W##S##_3.w, wh1v, lsum));                       \
        acc0 = __builtin_amdgcn_mfma_f32_16x16x32_bf16(af0, B##S##_0, acc0, 0, 0, 0);  \
        acc1 = __builtin_amdgcn_mfma_f32_16x16x32_bf16(af0, B##S##_2, acc1, 0, 0, 0);  \
        acc2 = __builtin_amdgcn_mfma_f32_16x16x32_bf16(af0, B##S##_4, acc2, 0, 0, 0);  \
        acc3 = __builtin_amdgcn_mfma_f32_16x16x32_bf16(af0, B##S##_6, acc3, 0, 0, 0);  \
        acc0 = __builtin_amdgcn_mfma_f32_16x16x32_bf16(af1, B##S##_1, acc0, 0, 0, 0);  \
        acc1 = __builtin_amdgcn_mfma_f32_16x16x32_bf16(af1, B##S##_3, acc1, 0, 0, 0);  \
        acc2 = __builtin_amdgcn_mfma_f32_16x16x32_bf16(af1, B##S##_5, acc2, 0, 0, 0);  \
        acc3 = __builtin_amdgcn_mfma_f32_16x16x32_bf16(af1, B##S##_7, acc3, 0, 0, 0);  \
    }

    // prologue: 2 groups in flight
    ISSUE(0, 0);
    ISSUE(1, 1);

    // steady state: 3 groups (48 ops) in flight; wait vmcnt(32) -> oldest group done
    for (int it = 0; it < 10; ++it) {
        const int c = it * 3;
        ISSUE(c + 2, 2);  COMPUTE(0, "32");
        ISSUE(c + 3, 0);  COMPUTE(1, "32");
        ISSUE(c + 4, 1);  COMPUTE(2, "32");
    }
    // tail: chunks 30 (set 0), 31 (set 1)
    COMPUTE(0, "16");
    COMPUTE(1, "0");

#undef ISSUE
#undef COMPUTE

    // lsum: sum the 4 g-subgroups holding the same row
    lsum += __shfl_xor(lsum, 16);
    lsum += __shfl_xor(lsum, 32);

    __syncthreads();   // everyone done with mbuf before aliasing as accbuf

    // D layout (m89): row = g*4 + r, col = i16
    #pragma unroll
    for (int r = 0; r < 4; ++r) {
        accbuf[wave][g*4 + r][ 0 + i16] = acc0[r];
        accbuf[wave][g*4 + r][16 + i16] = acc1[r];
        accbuf[wave][g*4 + r][32 + i16] = acc2[r];
        accbuf[wave][g*4 + r][48 + i16] = acc3[r];
    }
    if (lane < 16) lsumbuf[wave][lane] = lsum;
    __syncthreads();

    // merge 4 waves (disjoint col-windows of the same 16 rows), normalize, ELU, store
    const int tr  = tid >> 4;
    const int tf4 = (tid & 15) * 4;
    float4 s0 = *(const float4*)&accbuf[0][tr][tf4];
    float4 s1 = *(const float4*)&accbuf[1][tr][tf4];
    float4 s2 = *(const float4*)&accbuf[2][tr][tf4];
    float4 s3 = *(const float4*)&accbuf[3][tr][tf4];
    float L = lsumbuf[0][tr] + lsumbuf[1][tr] + lsumbuf[2][tr] + lsumbuf[3][tr];
    const float inv = (L > 0.f) ? 1.f / L : 0.f;
    float4 o;
    o.x = (s0.x + s1.x + s2.x + s3.x) * inv;
    o.y = (s0.y + s1.y + s2.y + s3.y) * inv;
    o.z = (s0.z + s1.z + s2.z + s3.z) * inv;
    o.w = (s0.w + s1.w + s2.w + s3.w) * inv;
    o.x = (o.x > 0.f) ? o.x : (__expf(o.x) - 1.f);
    o.y = (o.y > 0.f) ? o.y : (__expf(o.y) - 1.f);
    o.z = (o.z > 0.f) ? o.z : (__expf(o.z) - 1.f);
    o.w = (o.w > 0.f) ? o.w : (__expf(o.w) - 1.f);
    *(float4*)&out[(size_t)(R + tr) * D_OUT + tf4] = o;
}

extern "C" void kernel_launch(void* const* d_in, const int* in_sizes, int n_in,
                              void* d_out, int out_size, void* d_ws, size_t ws_size,
                              hipStream_t stream) {
    const float* h    = (const float*)d_in[0];
    const float* mask = (const float*)d_in[1];
    // d_in[2] = lamda: unused (dischange==0 makes the mask-update a no-op)
    const float* W    = (const float*)d_in[3];
    const float* a    = (const float*)d_in[4];
    float* out = (float*)d_out;

    // ws: WhTp bf16 [64][8192] (1MB) | Wh1 (32KB) | Wh2 (32KB)
    unsigned short* WhTp = (unsigned short*)d_ws;
    float* Wh1 = (float*)((char*)d_ws + (size_t)D_OUT * N_NODES * sizeof(unsigned short));
    float* Wh2 = Wh1 + N_NODES;

    k_gemm_wh<<<N_NODES / 32, 256, 0, stream>>>(h, W, a, WhTp, Wh1, Wh2);
    k_fused<<<N_NODES / 16, 256, 0, stream>>>(mask, WhTp, Wh1, Wh2, out);
}